// Round 13
// baseline (394.409 us; speedup 1.0000x reference)
//
#include <hip/hip_runtime.h>
#include <hip/hip_bf16.h>

#define NEG_SLOPE 0.2f

typedef __attribute__((ext_vector_type(8))) short bf16x8;
typedef __attribute__((ext_vector_type(4))) float f32x4;

// split f32 -> bf16 hi + bf16 lo (RNE both); x ~= hi + lo with ~2^-17 residual
__device__ __forceinline__ void splitf(float x, unsigned short& h, unsigned short& l)
{
    const unsigned int u  = __float_as_uint(x);
    const unsigned int uh = (u + 0x7fffu + ((u >> 16) & 1u)) >> 16;
    const float        fh = __uint_as_float(uh << 16);
    const float        r  = x - fh;
    const unsigned int ur = __float_as_uint(r);
    const unsigned int ul = (ur + 0x7fffu + ((ur >> 16) & 1u)) >> 16;
    h = (unsigned short)uh;
    l = (unsigned short)ul;
}

// ---------------------------------------------------------------------------
// PREP: blocks 0..255 pre-split+transpose the 4 weight matrices
// (W[k][n] f32 -> Wt_hi/lo[mat][n][k] bf16); blocks 256+ count in-degrees.
// One dispatch instead of five (launch-gap reduction, R12 post-mortem).
// ---------------------------------------------------------------------------
__global__ __launch_bounds__(256) void prep(
    const float* __restrict__ Wq, const float* __restrict__ Wk,
    const float* __restrict__ Wv, const float* __restrict__ Wo,
    unsigned short* __restrict__ Wth, unsigned short* __restrict__ Wtl,
    const int* __restrict__ tgt, int* __restrict__ cnt, int E)
{
    const int bid = blockIdx.x;
    if (bid < 256) {
        const int mat = bid >> 6;
        const float* __restrict__ W =
            (mat == 0) ? Wq : ((mat == 1) ? Wk : ((mat == 2) ? Wv : Wo));
        const int t = (bid & 63) * 256 + threadIdx.x;   // 0..16383
        const int k = t >> 7, n = t & 127;
        unsigned short h, l;
        splitf(W[k * 128 + n], h, l);
        Wth[mat * 16384 + n * 128 + k] = h;
        Wtl[mat * 16384 + n * 128 + k] = l;
    } else {
        const int e = (bid - 256) * 256 + threadIdx.x;
        if (e < E) atomicAdd(cnt + tgt[e], 1);
    }
}

// ---------------------------------------------------------------------------
// Single-kernel exclusive scan of cnt[V] -> offs, fill. One block of 1024.
// Replaces scan1+scan2+scan3 (3 launches -> 1; ~600 KB traffic, few us).
// ---------------------------------------------------------------------------
__global__ __launch_bounds__(1024) void scan_all(
    const int* __restrict__ cnt, int* __restrict__ offs,
    int* __restrict__ fill, int V)
{
    __shared__ int sh[1024];
    const int t = threadIdx.x;
    const int per = (V + 1023) / 1024;
    const int beg = min(t * per, V);
    const int end = min(beg + per, V);
    int s = 0;
    for (int i = beg; i < end; ++i) s += cnt[i];
    sh[t] = s;
    __syncthreads();
    for (int off = 1; off < 1024; off <<= 1) {
        const int x = (t >= off) ? sh[t - off] : 0;
        __syncthreads();
        sh[t] += x;
        __syncthreads();
    }
    int run = (t > 0) ? sh[t - 1] : 0;
    for (int i = beg; i < end; ++i) {
        offs[i] = run;
        fill[i] = run;
        run += cnt[i];
    }
}

// ---------------------------------------------------------------------------
// Scatter edges into target-sorted order: packed (src, edge weight) int2.
// ---------------------------------------------------------------------------
__global__ __launch_bounds__(256) void scatter_edges(
    const int* __restrict__ src, const int* __restrict__ tgt,
    const float* __restrict__ ew, int* __restrict__ fill,
    int2* __restrict__ se, int E)
{
    const int e = blockIdx.x * blockDim.x + threadIdx.x;
    if (e >= E) return;
    const int pos = atomicAdd(fill + tgt[e], 1);
    se[pos] = make_int2(src[e], __float_as_int(ew[e]));
}

// ---------------------------------------------------------------------------
// Fused QKV split-precision MFMA GEMM: stages + splits the 64x128 A-tile
// ONCE per block, then loops m in {Q,K,V} (R12 fix: grid.y=3 re-read and
// re-split A 3x). A*B ~= Ah*Bh + Ah*Bl + Al*Bh, f32 MFMA accum (7e-5 ok).
// LDS 54 KB -> 2 blocks/CU. Ash rows 136 shorts (272 B): frag b128 reads
// 2-way max (free). Frag layout as R12 (verified absmax 0.0039).
// ---------------------------------------------------------------------------
__global__ __launch_bounds__(256) void gemm_qkv3(
    const float* __restrict__ A,
    const unsigned short* __restrict__ Wth, const unsigned short* __restrict__ Wtl,
    const float* __restrict__ bq, const float* __restrict__ bk,
    const float* __restrict__ bv,
    float* __restrict__ D0, float* __restrict__ D1, float* __restrict__ D2,
    int V)
{
    __shared__ unsigned short Ash[64][136], Asl[64][136];   // 34 KB
    __shared__ unsigned short Bsh[128][40], Bsl[128][40];   // 20 KB

    const int tid  = threadIdx.x;
    const int w    = tid >> 6;
    const int l    = tid & 63;
    const int row0 = blockIdx.x * 64;

    // stage + split whole A tile (64 rows x 128 k) once
    {
        const int srow = tid >> 2;
        const int sk0  = (tid & 3) * 32;
        const int gr   = row0 + srow;
#pragma unroll
        for (int c = 0; c < 4; ++c) {
            float x[8] = {0.f, 0.f, 0.f, 0.f, 0.f, 0.f, 0.f, 0.f};
            if (gr < V) {
                const float4 a0 = *(const float4*)(A + (size_t)gr * 128 + sk0 + c * 8);
                const float4 a1 = *(const float4*)(A + (size_t)gr * 128 + sk0 + c * 8 + 4);
                x[0] = a0.x; x[1] = a0.y; x[2] = a0.z; x[3] = a0.w;
                x[4] = a1.x; x[5] = a1.y; x[6] = a1.z; x[7] = a1.w;
            }
            bf16x8 vh, vl;
#pragma unroll
            for (int i = 0; i < 8; ++i) {
                unsigned short hh, ll;
                splitf(x[i], hh, ll);
                vh[i] = (short)hh; vl[i] = (short)ll;
            }
            *(bf16x8*)&Ash[srow][sk0 + c * 8] = vh;
            *(bf16x8*)&Asl[srow][sk0 + c * 8] = vl;
        }
    }
    __syncthreads();

    const int ar   = w * 16 + (l & 15);
    const int kc8  = (l >> 4) * 8;
    const int colb = l & 15;
    const int rsub = (l >> 4) * 4;

    for (int m = 0; m < 3; ++m) {
        const unsigned short* __restrict__ Wh = Wth + m * 16384;
        const unsigned short* __restrict__ Wl = Wtl + m * 16384;
        const float* __restrict__ bias = (m == 0) ? bq : ((m == 1) ? bk : bv);
        float* __restrict__ D          = (m == 0) ? D0 : ((m == 1) ? D1 : D2);

        f32x4 acc[8];
#pragma unroll
        for (int t = 0; t < 8; ++t) acc[t] = (f32x4){0.f, 0.f, 0.f, 0.f};

        for (int k0 = 0; k0 < 128; k0 += 32) {
            // stage B (128 cols x 32 k) hi/lo
#pragma unroll
            for (int r = 0; r < 2; ++r) {
                const int idx = tid + r * 256;
                const int n = idx >> 2, bkc = (idx & 3) * 8;
                *(bf16x8*)&Bsh[n][bkc] = *(const bf16x8*)(Wh + n * 128 + k0 + bkc);
                *(bf16x8*)&Bsl[n][bkc] = *(const bf16x8*)(Wl + n * 128 + k0 + bkc);
            }
            __syncthreads();

            const bf16x8 ah = *(const bf16x8*)&Ash[ar][k0 + kc8];
            const bf16x8 al = *(const bf16x8*)&Asl[ar][k0 + kc8];
#pragma unroll
            for (int t = 0; t < 8; ++t) {
                const int col = t * 16 + colb;
                const bf16x8 bh = *(const bf16x8*)&Bsh[col][kc8];
                const bf16x8 bl = *(const bf16x8*)&Bsl[col][kc8];
                acc[t] = __builtin_amdgcn_mfma_f32_16x16x32_bf16(ah, bh, acc[t], 0, 0, 0);
                acc[t] = __builtin_amdgcn_mfma_f32_16x16x32_bf16(ah, bl, acc[t], 0, 0, 0);
                acc[t] = __builtin_amdgcn_mfma_f32_16x16x32_bf16(al, bh, acc[t], 0, 0, 0);
            }
            __syncthreads();
        }

        // epilogue: bias; C/D frag col=lane&15, row=(lane>>4)*4+r
#pragma unroll
        for (int t = 0; t < 8; ++t) {
            const int col = t * 16 + colb;
            const float bv_ = bias[col];
#pragma unroll
            for (int r = 0; r < 4; ++r) {
                const int grow = row0 + w * 16 + rsub + r;
                if (grow < V)
                    D[(size_t)grow * 128 + col] = acc[t][r] + bv_;
            }
        }
    }
}

// ---------------------------------------------------------------------------
// Split-precision MFMA GEMM (single W), for the final projection + lrelu.
// Same structure as R12's gemm_mfma (verified).
// ---------------------------------------------------------------------------
__global__ __launch_bounds__(256) void gemm_mfma(
    const float* __restrict__ A,
    const unsigned short* __restrict__ Wth, const unsigned short* __restrict__ Wtl,
    const float* __restrict__ bias, float* __restrict__ D, int V)
{
    __shared__ unsigned short Ash[64][40], Asl[64][40];
    __shared__ unsigned short Bsh[128][40], Bsl[128][40];

    const int tid  = threadIdx.x;
    const int w    = tid >> 6;
    const int l    = tid & 63;
    const int row0 = blockIdx.x * 64;

    const int srow = tid >> 2;
    const int skc  = tid & 3;

    f32x4 acc[8];
#pragma unroll
    for (int t = 0; t < 8; ++t) acc[t] = (f32x4){0.f, 0.f, 0.f, 0.f};

    for (int k0 = 0; k0 < 128; k0 += 32) {
        {
            const int gr = row0 + srow;
            float x[8] = {0.f, 0.f, 0.f, 0.f, 0.f, 0.f, 0.f, 0.f};
            if (gr < V) {
                const float4 a0 = *(const float4*)(A + (size_t)gr * 128 + k0 + skc * 8);
                const float4 a1 = *(const float4*)(A + (size_t)gr * 128 + k0 + skc * 8 + 4);
                x[0] = a0.x; x[1] = a0.y; x[2] = a0.z; x[3] = a0.w;
                x[4] = a1.x; x[5] = a1.y; x[6] = a1.z; x[7] = a1.w;
            }
            bf16x8 vh, vl;
#pragma unroll
            for (int i = 0; i < 8; ++i) {
                unsigned short hh, ll;
                splitf(x[i], hh, ll);
                vh[i] = (short)hh; vl[i] = (short)ll;
            }
            *(bf16x8*)&Ash[srow][skc * 8] = vh;
            *(bf16x8*)&Asl[srow][skc * 8] = vl;
        }
#pragma unroll
        for (int r = 0; r < 2; ++r) {
            const int idx = tid + r * 256;
            const int n = idx >> 2, bkc = idx & 3;
            *(bf16x8*)&Bsh[n][bkc * 8] = *(const bf16x8*)(Wth + n * 128 + k0 + bkc * 8);
            *(bf16x8*)&Bsl[n][bkc * 8] = *(const bf16x8*)(Wtl + n * 128 + k0 + bkc * 8);
        }
        __syncthreads();

        const int ar  = w * 16 + (l & 15);
        const int kc8 = (l >> 4) * 8;
        const bf16x8 ah = *(const bf16x8*)&Ash[ar][kc8];
        const bf16x8 al = *(const bf16x8*)&Asl[ar][kc8];
#pragma unroll
        for (int t = 0; t < 8; ++t) {
            const int col = t * 16 + (l & 15);
            const bf16x8 bh = *(const bf16x8*)&Bsh[col][kc8];
            const bf16x8 bl = *(const bf16x8*)&Bsl[col][kc8];
            acc[t] = __builtin_amdgcn_mfma_f32_16x16x32_bf16(ah, bh, acc[t], 0, 0, 0);
            acc[t] = __builtin_amdgcn_mfma_f32_16x16x32_bf16(ah, bl, acc[t], 0, 0, 0);
            acc[t] = __builtin_amdgcn_mfma_f32_16x16x32_bf16(al, bh, acc[t], 0, 0, 0);
        }
        __syncthreads();
    }

    const int colb = l & 15;
    const int rsub = (l >> 4) * 4;
#pragma unroll
    for (int t = 0; t < 8; ++t) {
        const int col = t * 16 + colb;
        const float bv_ = bias[col];
#pragma unroll
        for (int r = 0; r < 4; ++r) {
            const int grow = row0 + w * 16 + rsub + r;
            if (grow < V) {
                float xx = acc[t][r] + bv_;
                xx = (xx > 0.f) ? xx : NEG_SLOPE * xx;
                D[(size_t)grow * 128 + col] = xx;
            }
        }
    }
}

// ---------------------------------------------------------------------------
// Fused per-node kernel (all f32): QK^T + exp + denom + weighted Vv
// aggregation + normalization. One wave per node, STATIC mapping -- best of
// five scheduling variants (R4-R11); ~119 us, near the random-gather
// L2-miss floor (388 MB @ ~3.5 TB/s). Ksh padded [4][36]: conflict-free.
// ---------------------------------------------------------------------------
__global__ __launch_bounds__(256) void fused_agg(
    const float* __restrict__ Q, const float* __restrict__ K,
    const float* __restrict__ Vv, const int2* __restrict__ se,
    const int* __restrict__ offs, const int* __restrict__ fill,
    const float* __restrict__ Wei, const float* __restrict__ bei,
    float* __restrict__ accum, int V)
{
    __shared__ float Ksh[4][4][36];
    const int wid = threadIdx.x >> 6;
    const int node = blockIdx.x * 4 + wid;
    if (node >= V) return;
    const int l   = threadIdx.x & 63;
    const int h   = l & 3;
    const int hd  = l >> 4;
    const float weH = Wei[h], beH = bei[h];
    const float2* __restrict__ Vv2 = (const float2*)Vv;

    {
        const float2 kk = *(const float2*)(K + (size_t)node * 128 + l * 2);
        const int f0 = l * 2;
        Ksh[wid][f0 >> 5][f0 & 31] = kk.x;
        Ksh[wid][(f0 + 1) >> 5][(f0 + 1) & 31] = kk.y;
    }

    const int start = offs[node];
    const int end   = fill[node];

    float degacc = 0.f;
    float ax = 0.f, ay = 0.f;

    for (int b0 = start; b0 < end; b0 += 16) {
        const int nj = min(16, end - b0);
        const int jj = l >> 2;
        int   s = 0;
        float w = 0.f, p = 0.f;
        if (jj < nj) {
            const int2 t = se[b0 + jj];
            s = t.x;
            w = __int_as_float(t.y);
            const float4* qp = (const float4*)(Q + (size_t)s * 128 + h * 32);
            float dot = 0.f;
#pragma unroll
            for (int i = 0; i < 8; ++i) {
                const float4 q = qp[i];
                const float4 k = *(const float4*)&Ksh[wid][h][i * 4];
                dot += q.x * k.x + q.y * k.y + q.z * k.z + q.w * k.w;
            }
            float bb = fmaf(w, weH, beH);
            bb = (bb > 0.f) ? bb : NEG_SLOPE * bb;
            p = __expf(fmaf(dot, 0.17677669529663687f, bb));
        }
        degacc += p;
        const float coef = p * w;

        if (nj == 16) {
#pragma unroll
            for (int j = 0; j < 16; ++j) {
                const float cj = __shfl(coef, j * 4 + hd);
                const int   sj = __shfl(s,    j * 4);
                const float2 v = Vv2[(size_t)sj * 64 + l];
                ax = fmaf(cj, v.x, ax);
                ay = fmaf(cj, v.y, ay);
            }
        } else {
            for (int j = 0; j < nj; ++j) {
                const float cj = __shfl(coef, j * 4 + hd);
                const int   sj = __shfl(s,    j * 4);
                const float2 v = Vv2[(size_t)sj * 64 + l];
                ax = fmaf(cj, v.x, ax);
                ay = fmaf(cj, v.y, ay);
            }
        }
    }

    float d = degacc;
    d += __shfl_xor(d, 4);
    d += __shfl_xor(d, 8);
    d += __shfl_xor(d, 16);
    d += __shfl_xor(d, 32);
    const float deg = __shfl(d, hd);
    const float inv = 1.0f / (deg + 1e-16f);

    *(float2*)(accum + (size_t)node * 128 + l * 2) =
        make_float2(ax * inv, ay * inv);
}

// ---------------------------------------------------------------------------
extern "C" void kernel_launch(void* const* d_in, const int* in_sizes, int n_in,
                              void* d_out, int out_size, void* d_ws, size_t ws_size,
                              hipStream_t stream)
{
    const float* h   = (const float*)d_in[0];
    const int*   ei  = (const int*)  d_in[1];
    const float* ew  = (const float*)d_in[2];
    const float* Wq  = (const float*)d_in[3];
    const float* bq  = (const float*)d_in[4];
    const float* Wk  = (const float*)d_in[5];
    const float* bk  = (const float*)d_in[6];
    const float* Wv  = (const float*)d_in[7];
    const float* bv  = (const float*)d_in[8];
    const float* Wo  = (const float*)d_in[9];
    const float* bo  = (const float*)d_in[10];
    const float* Wei = (const float*)d_in[11];
    const float* bei = (const float*)d_in[12];

    const int V = in_sizes[0] / 128;
    const int E = in_sizes[2];
    const int* src = ei;
    const int* tgt = ei + E;

    // workspace layout
    float* Q     = (float*)d_ws;
    float* Km    = Q  + (size_t)V * 128;
    float* Vm    = Km + (size_t)V * 128;
    float* accum = Vm + (size_t)V * 128;
    unsigned short* Wth = (unsigned short*)(accum + (size_t)V * 128); // [4][128][128]
    unsigned short* Wtl = Wth + 4 * 16384;
    int2*  se    = (int2*)(Wtl + 4 * 16384);
    int*   cnt   = (int*)(se + E);
    int*   offs  = cnt  + V;
    int*   fill  = offs + V + 1;

    hipMemsetAsync(cnt, 0, (size_t)V * sizeof(int), stream);

    // prep: 4 weight splits (blocks 0..255) + in-degree count (rest)
    prep<<<256 + (E + 255) / 256, 256, 0, stream>>>(
        Wq, Wk, Wv, Wo, Wth, Wtl, tgt, cnt, E);

    scan_all<<<1, 1024, 0, stream>>>(cnt, offs, fill, V);

    scatter_edges<<<(E + 255) / 256, 256, 0, stream>>>(
        src, tgt, ew, fill, se, E);

    const int mfGrid = (V + 63) / 64;
    gemm_qkv3<<<mfGrid, 256, 0, stream>>>(
        h, Wth, Wtl, bq, bk, bv, Q, Km, Vm, V);

    fused_agg<<<(V + 3) / 4, 256, 0, stream>>>(
        Q, Km, Vm, se, offs, fill, Wei, bei, accum, V);

    gemm_mfma<<<mfGrid, 256, 0, stream>>>(
        accum, Wth + 3 * 16384, Wtl + 3 * 16384, bo, (float*)d_out, V);
}

// Round 14
// 376.399 us; speedup vs baseline: 1.0478x; 1.0478x over previous
//
#include <hip/hip_runtime.h>
#include <hip/hip_bf16.h>

#define NEG_SLOPE 0.2f

typedef __attribute__((ext_vector_type(8))) short bf16x8;
typedef __attribute__((ext_vector_type(4))) float f32x4;

// split f32 -> bf16 hi + bf16 lo (RNE both); x ~= hi + lo with ~2^-17 residual
__device__ __forceinline__ void splitf(float x, unsigned short& h, unsigned short& l)
{
    const unsigned int u  = __float_as_uint(x);
    const unsigned int uh = (u + 0x7fffu + ((u >> 16) & 1u)) >> 16;
    const float        fh = __uint_as_float(uh << 16);
    const float        r  = x - fh;
    const unsigned int ur = __float_as_uint(r);
    const unsigned int ul = (ur + 0x7fffu + ((ur >> 16) & 1u)) >> 16;
    h = (unsigned short)uh;
    l = (unsigned short)ul;
}

// ---------------------------------------------------------------------------
// PREP: blocks 0..255 pre-split+transpose the 4 weight matrices
// (W[k][n] f32 -> Wt_hi/lo[mat][n][k] bf16); blocks 256+ count in-degrees.
// Launch-count reduction only -- per-thread work identical to R12's pieces.
// ---------------------------------------------------------------------------
__global__ __launch_bounds__(256) void prep(
    const float* __restrict__ Wq, const float* __restrict__ Wk,
    const float* __restrict__ Wv, const float* __restrict__ Wo,
    unsigned short* __restrict__ Wth, unsigned short* __restrict__ Wtl,
    const int* __restrict__ tgt, int* __restrict__ cnt, int E)
{
    const int bid = blockIdx.x;
    if (bid < 256) {
        const int mat = bid >> 6;
        const float* __restrict__ W =
            (mat == 0) ? Wq : ((mat == 1) ? Wk : ((mat == 2) ? Wv : Wo));
        const int t = (bid & 63) * 256 + threadIdx.x;   // 0..16383
        const int k = t >> 7, n = t & 127;
        unsigned short h, l;
        splitf(W[k * 128 + n], h, l);
        Wth[mat * 16384 + n * 128 + k] = h;
        Wtl[mat * 16384 + n * 128 + k] = l;
    } else {
        const int e = (bid - 256) * 256 + threadIdx.x;
        if (e < E) atomicAdd(cnt + tgt[e], 1);
    }
}

// ---------------------------------------------------------------------------
// Single-kernel exclusive scan of cnt[V] -> offs, fill. One block of 1024.
// ---------------------------------------------------------------------------
__global__ __launch_bounds__(1024) void scan_all(
    const int* __restrict__ cnt, int* __restrict__ offs,
    int* __restrict__ fill, int V)
{
    __shared__ int sh[1024];
    const int t = threadIdx.x;
    const int per = (V + 1023) / 1024;
    const int beg = min(t * per, V);
    const int end = min(beg + per, V);
    int s = 0;
    for (int i = beg; i < end; ++i) s += cnt[i];
    sh[t] = s;
    __syncthreads();
    for (int off = 1; off < 1024; off <<= 1) {
        const int x = (t >= off) ? sh[t - off] : 0;
        __syncthreads();
        sh[t] += x;
        __syncthreads();
    }
    int run = (t > 0) ? sh[t - 1] : 0;
    for (int i = beg; i < end; ++i) {
        offs[i] = run;
        fill[i] = run;
        run += cnt[i];
    }
}

// ---------------------------------------------------------------------------
// Scatter edges into target-sorted order: packed (src, edge weight) int2.
// ---------------------------------------------------------------------------
__global__ __launch_bounds__(256) void scatter_edges(
    const int* __restrict__ src, const int* __restrict__ tgt,
    const float* __restrict__ ew, int* __restrict__ fill,
    int2* __restrict__ se, int E)
{
    const int e = blockIdx.x * blockDim.x + threadIdx.x;
    if (e >= E) return;
    const int pos = atomicAdd(fill + tgt[e], 1);
    se[pos] = make_int2(src[e], __float_as_int(ew[e]));
}

// ---------------------------------------------------------------------------
// Split-precision MFMA GEMM (R12-exact, 294.7us-verified): D = act(A@W+b).
// A*B ~= Ah*Bh + Ah*Bl + Al*Bh, f32 MFMA accum. 30 KB LDS -> 5 blocks/CU
// (R13 lesson: the 55 KB fused-A variant dropped occupancy to 2/CU and
// regressed ~100us total -- big-LDS fusion loses to occupancy here).
// ---------------------------------------------------------------------------
__global__ __launch_bounds__(256) void gemm_mfma(
    const float* __restrict__ A,
    const unsigned short* __restrict__ Bh0, const unsigned short* __restrict__ Bl0,
    const unsigned short* __restrict__ Bh1, const unsigned short* __restrict__ Bl1,
    const unsigned short* __restrict__ Bh2, const unsigned short* __restrict__ Bl2,
    const float* __restrict__ b0, const float* __restrict__ b1, const float* __restrict__ b2,
    float* __restrict__ D0, float* __restrict__ D1, float* __restrict__ D2,
    int V, int lrelu)
{
    __shared__ unsigned short Ash[64][40], Asl[64][40];     // 10 KB
    __shared__ unsigned short Bsh[128][40], Bsl[128][40];   // 20 KB

    const int m = blockIdx.y;
    const unsigned short* __restrict__ Wth = (m == 0) ? Bh0 : ((m == 1) ? Bh1 : Bh2);
    const unsigned short* __restrict__ Wtl = (m == 0) ? Bl0 : ((m == 1) ? Bl1 : Bl2);
    const float* __restrict__ bias         = (m == 0) ? b0  : ((m == 1) ? b1  : b2);
    float* __restrict__ D                  = (m == 0) ? D0  : ((m == 1) ? D1  : D2);

    const int tid  = threadIdx.x;
    const int w    = tid >> 6;
    const int l    = tid & 63;
    const int row0 = blockIdx.x * 64;

    const int srow = tid >> 2;      // A staging: row 0..63
    const int skc  = tid & 3;       // A staging: k-chunk 0..3

    f32x4 acc[8];
#pragma unroll
    for (int t = 0; t < 8; ++t) acc[t] = (f32x4){0.f, 0.f, 0.f, 0.f};

    for (int k0 = 0; k0 < 128; k0 += 32) {
        // stage A (64 rows x 32 k), f32 -> hi/lo bf16
        {
            const int gr = row0 + srow;
            float x[8] = {0.f, 0.f, 0.f, 0.f, 0.f, 0.f, 0.f, 0.f};
            if (gr < V) {
                const float4 a0 = *(const float4*)(A + (size_t)gr * 128 + k0 + skc * 8);
                const float4 a1 = *(const float4*)(A + (size_t)gr * 128 + k0 + skc * 8 + 4);
                x[0] = a0.x; x[1] = a0.y; x[2] = a0.z; x[3] = a0.w;
                x[4] = a1.x; x[5] = a1.y; x[6] = a1.z; x[7] = a1.w;
            }
            bf16x8 vh, vl;
#pragma unroll
            for (int i = 0; i < 8; ++i) {
                unsigned short hh, ll;
                splitf(x[i], hh, ll);
                vh[i] = (short)hh; vl[i] = (short)ll;
            }
            *(bf16x8*)&Ash[srow][skc * 8] = vh;
            *(bf16x8*)&Asl[srow][skc * 8] = vl;
        }
        // stage B (128 cols x 32 k) from pre-split transposed weights
#pragma unroll
        for (int r = 0; r < 2; ++r) {
            const int idx = tid + r * 256;
            const int n = idx >> 2, bkc = idx & 3;
            *(bf16x8*)&Bsh[n][bkc * 8] = *(const bf16x8*)(Wth + n * 128 + k0 + bkc * 8);
            *(bf16x8*)&Bsl[n][bkc * 8] = *(const bf16x8*)(Wtl + n * 128 + k0 + bkc * 8);
        }
        __syncthreads();

        const int ar  = w * 16 + (l & 15);
        const int kc8 = (l >> 4) * 8;
        const bf16x8 ah = *(const bf16x8*)&Ash[ar][kc8];
        const bf16x8 al = *(const bf16x8*)&Asl[ar][kc8];
#pragma unroll
        for (int t = 0; t < 8; ++t) {
            const int col = t * 16 + (l & 15);
            const bf16x8 bh = *(const bf16x8*)&Bsh[col][kc8];
            const bf16x8 bl = *(const bf16x8*)&Bsl[col][kc8];
            acc[t] = __builtin_amdgcn_mfma_f32_16x16x32_bf16(ah, bh, acc[t], 0, 0, 0);
            acc[t] = __builtin_amdgcn_mfma_f32_16x16x32_bf16(ah, bl, acc[t], 0, 0, 0);
            acc[t] = __builtin_amdgcn_mfma_f32_16x16x32_bf16(al, bh, acc[t], 0, 0, 0);
        }
        __syncthreads();
    }

    // epilogue: bias + optional lrelu; C/D frag col=lane&15, row=(lane>>4)*4+r
    const int colb = l & 15;
    const int rsub = (l >> 4) * 4;
#pragma unroll
    for (int t = 0; t < 8; ++t) {
        const int col = t * 16 + colb;
        const float bv = bias[col];
#pragma unroll
        for (int r = 0; r < 4; ++r) {
            const int grow = row0 + w * 16 + rsub + r;
            if (grow < V) {
                float xx = acc[t][r] + bv;
                if (lrelu) xx = (xx > 0.f) ? xx : NEG_SLOPE * xx;
                D[(size_t)grow * 128 + col] = xx;
            }
        }
    }
}

// ---------------------------------------------------------------------------
// Fused per-node kernel (all f32): QK^T + exp + denom + weighted Vv
// aggregation + normalization. One wave per node, STATIC mapping -- best of
// five scheduling variants (R4-R11); ~119 us, near the random-gather
// L2-miss floor (388 MB @ ~3.5 TB/s). Ksh padded [4][36]: conflict-free.
// ---------------------------------------------------------------------------
__global__ __launch_bounds__(256) void fused_agg(
    const float* __restrict__ Q, const float* __restrict__ K,
    const float* __restrict__ Vv, const int2* __restrict__ se,
    const int* __restrict__ offs, const int* __restrict__ fill,
    const float* __restrict__ Wei, const float* __restrict__ bei,
    float* __restrict__ accum, int V)
{
    __shared__ float Ksh[4][4][36];
    const int wid = threadIdx.x >> 6;
    const int node = blockIdx.x * 4 + wid;
    if (node >= V) return;
    const int l   = threadIdx.x & 63;
    const int h   = l & 3;
    const int hd  = l >> 4;
    const float weH = Wei[h], beH = bei[h];
    const float2* __restrict__ Vv2 = (const float2*)Vv;

    {
        const float2 kk = *(const float2*)(K + (size_t)node * 128 + l * 2);
        const int f0 = l * 2;
        Ksh[wid][f0 >> 5][f0 & 31] = kk.x;
        Ksh[wid][(f0 + 1) >> 5][(f0 + 1) & 31] = kk.y;
    }

    const int start = offs[node];
    const int end   = fill[node];

    float degacc = 0.f;
    float ax = 0.f, ay = 0.f;

    for (int b0 = start; b0 < end; b0 += 16) {
        const int nj = min(16, end - b0);
        const int jj = l >> 2;
        int   s = 0;
        float w = 0.f, p = 0.f;
        if (jj < nj) {
            const int2 t = se[b0 + jj];
            s = t.x;
            w = __int_as_float(t.y);
            const float4* qp = (const float4*)(Q + (size_t)s * 128 + h * 32);
            float dot = 0.f;
#pragma unroll
            for (int i = 0; i < 8; ++i) {
                const float4 q = qp[i];
                const float4 k = *(const float4*)&Ksh[wid][h][i * 4];
                dot += q.x * k.x + q.y * k.y + q.z * k.z + q.w * k.w;
            }
            float bb = fmaf(w, weH, beH);
            bb = (bb > 0.f) ? bb : NEG_SLOPE * bb;
            p = __expf(fmaf(dot, 0.17677669529663687f, bb));
        }
        degacc += p;
        const float coef = p * w;

        if (nj == 16) {
#pragma unroll
            for (int j = 0; j < 16; ++j) {
                const float cj = __shfl(coef, j * 4 + hd);
                const int   sj = __shfl(s,    j * 4);
                const float2 v = Vv2[(size_t)sj * 64 + l];
                ax = fmaf(cj, v.x, ax);
                ay = fmaf(cj, v.y, ay);
            }
        } else {
            for (int j = 0; j < nj; ++j) {
                const float cj = __shfl(coef, j * 4 + hd);
                const int   sj = __shfl(s,    j * 4);
                const float2 v = Vv2[(size_t)sj * 64 + l];
                ax = fmaf(cj, v.x, ax);
                ay = fmaf(cj, v.y, ay);
            }
        }
    }

    float d = degacc;
    d += __shfl_xor(d, 4);
    d += __shfl_xor(d, 8);
    d += __shfl_xor(d, 16);
    d += __shfl_xor(d, 32);
    const float deg = __shfl(d, hd);
    const float inv = 1.0f / (deg + 1e-16f);

    *(float2*)(accum + (size_t)node * 128 + l * 2) =
        make_float2(ax * inv, ay * inv);
}

// ---------------------------------------------------------------------------
extern "C" void kernel_launch(void* const* d_in, const int* in_sizes, int n_in,
                              void* d_out, int out_size, void* d_ws, size_t ws_size,
                              hipStream_t stream)
{
    const float* h   = (const float*)d_in[0];
    const int*   ei  = (const int*)  d_in[1];
    const float* ew  = (const float*)d_in[2];
    const float* Wq  = (const float*)d_in[3];
    const float* bq  = (const float*)d_in[4];
    const float* Wk  = (const float*)d_in[5];
    const float* bk  = (const float*)d_in[6];
    const float* Wv  = (const float*)d_in[7];
    const float* bv  = (const float*)d_in[8];
    const float* Wo  = (const float*)d_in[9];
    const float* bo  = (const float*)d_in[10];
    const float* Wei = (const float*)d_in[11];
    const float* bei = (const float*)d_in[12];

    const int V = in_sizes[0] / 128;
    const int E = in_sizes[2];
    const int* src = ei;
    const int* tgt = ei + E;

    // workspace layout
    float* Q     = (float*)d_ws;
    float* Km    = Q  + (size_t)V * 128;
    float* Vm    = Km + (size_t)V * 128;
    float* accum = Vm + (size_t)V * 128;
    unsigned short* Wth = (unsigned short*)(accum + (size_t)V * 128); // [4][128][128]
    unsigned short* Wtl = Wth + 4 * 16384;
    int2*  se    = (int2*)(Wtl + 4 * 16384);
    int*   cnt   = (int*)(se + E);
    int*   offs  = cnt  + V;
    int*   fill  = offs + V + 1;

    hipMemsetAsync(cnt, 0, (size_t)V * sizeof(int), stream);

    // prep: 4 weight splits (blocks 0..255) + in-degree count (rest)
    prep<<<256 + (E + 255) / 256, 256, 0, stream>>>(
        Wq, Wk, Wv, Wo, Wth, Wtl, tgt, cnt, E);

    scan_all<<<1, 1024, 0, stream>>>(cnt, offs, fill, V);

    scatter_edges<<<(E + 255) / 256, 256, 0, stream>>>(
        src, tgt, ew, fill, se, E);

    const int mfGrid = (V + 63) / 64;
    gemm_mfma<<<dim3(mfGrid, 3), 256, 0, stream>>>(
        h, Wth, Wtl, Wth + 16384, Wtl + 16384, Wth + 2 * 16384, Wtl + 2 * 16384,
        bq, bk, bv, Q, Km, Vm, V, 0);

    fused_agg<<<(V + 3) / 4, 256, 0, stream>>>(
        Q, Km, Vm, se, offs, fill, Wei, bei, accum, V);

    gemm_mfma<<<dim3(mfGrid, 1), 256, 0, stream>>>(
        accum, Wth + 3 * 16384, Wtl + 3 * 16384, Wth + 3 * 16384, Wtl + 3 * 16384,
        Wth + 3 * 16384, Wtl + 3 * 16384,
        bo, bo, bo, (float*)d_out, (float*)d_out, (float*)d_out, V, 1);
}

// Round 15
// 277.477 us; speedup vs baseline: 1.4214x; 1.3565x over previous
//
#include <hip/hip_runtime.h>
#include <hip/hip_bf16.h>

#define NEG_SLOPE 0.2f

typedef __attribute__((ext_vector_type(8))) short bf16x8;
typedef __attribute__((ext_vector_type(4))) float f32x4;

// split f32 -> bf16 hi + bf16 lo (RNE both); x ~= hi + lo with ~2^-17 residual
__device__ __forceinline__ void splitf(float x, unsigned short& h, unsigned short& l)
{
    const unsigned int u  = __float_as_uint(x);
    const unsigned int uh = (u + 0x7fffu + ((u >> 16) & 1u)) >> 16;
    const float        fh = __uint_as_float(uh << 16);
    const float        r  = x - fh;
    const unsigned int ur = __float_as_uint(r);
    const unsigned int ul = (ur + 0x7fffu + ((ur >> 16) & 1u)) >> 16;
    h = (unsigned short)uh;
    l = (unsigned short)ul;
}

// ---------------------------------------------------------------------------
// PREP: blocks 0..255 pre-split+transpose the 4 weight matrices
// (W[k][n] f32 -> Wt_hi/lo[mat][n][k] bf16); blocks 256+ count in-degrees.
// Parallel across 3381 blocks -- safe merge (unlike scan_all, R14 lesson:
// a single-block kernel with 600 KB of traffic is latency-bound on one CU's
// ~64 outstanding loads => ~60-80us; spread scans across blocks instead).
// ---------------------------------------------------------------------------
__global__ __launch_bounds__(256) void prep(
    const float* __restrict__ Wq, const float* __restrict__ Wk,
    const float* __restrict__ Wv, const float* __restrict__ Wo,
    unsigned short* __restrict__ Wth, unsigned short* __restrict__ Wtl,
    const int* __restrict__ tgt, int* __restrict__ cnt, int E)
{
    const int bid = blockIdx.x;
    if (bid < 256) {
        const int mat = bid >> 6;
        const float* __restrict__ W =
            (mat == 0) ? Wq : ((mat == 1) ? Wk : ((mat == 2) ? Wv : Wo));
        const int t = (bid & 63) * 256 + threadIdx.x;   // 0..16383
        const int k = t >> 7, n = t & 127;
        unsigned short h, l;
        splitf(W[k * 128 + n], h, l);
        Wth[mat * 16384 + n * 128 + k] = h;
        Wtl[mat * 16384 + n * 128 + k] = l;
    } else {
        const int e = (bid - 256) * 256 + threadIdx.x;
        if (e < E) atomicAdd(cnt + tgt[e], 1);
    }
}

// ---------------------------------------------------------------------------
// CSR build: block-wise exclusive scan of per-node counts (R12-exact --
// 49 blocks keep the 600 KB of scan traffic parallel across CUs)
// ---------------------------------------------------------------------------
__global__ __launch_bounds__(256) void scan1(const int* __restrict__ cnt,
                                             int* __restrict__ offs,
                                             int* __restrict__ bsums, int V)
{
    __shared__ int sh[256];
    const int t = threadIdx.x;
    const int base = blockIdx.x * 1024;
    int v[4];
    int s = 0;
#pragma unroll
    for (int i = 0; i < 4; ++i) {
        const int idx = base + t * 4 + i;
        v[i] = (idx < V) ? cnt[idx] : 0;
        s += v[i];
    }
    sh[t] = s;
    __syncthreads();
    for (int off = 1; off < 256; off <<= 1) {
        const int x = (t >= off) ? sh[t - off] : 0;
        __syncthreads();
        sh[t] += x;
        __syncthreads();
    }
    int run = (t > 0) ? sh[t - 1] : 0;
#pragma unroll
    for (int i = 0; i < 4; ++i) {
        const int idx = base + t * 4 + i;
        if (idx < V) offs[idx] = run;
        run += v[i];
    }
    if (t == 255) bsums[blockIdx.x] = sh[255];
}

__global__ void scan2(int* __restrict__ bsums, int nb)
{
    if (threadIdx.x == 0 && blockIdx.x == 0) {
        int run = 0;
        for (int i = 0; i < nb; ++i) { const int x = bsums[i]; bsums[i] = run; run += x; }
    }
}

__global__ __launch_bounds__(256) void scan3(int* __restrict__ offs,
                                             const int* __restrict__ bsums,
                                             int* __restrict__ fill, int V)
{
    const int v = blockIdx.x * blockDim.x + threadIdx.x;
    if (v >= V) return;
    const int o = offs[v] + bsums[v >> 10];
    offs[v] = o;
    fill[v] = o;
}

// ---------------------------------------------------------------------------
// Scatter edges into target-sorted order: packed (src, edge weight) int2.
// ---------------------------------------------------------------------------
__global__ __launch_bounds__(256) void scatter_edges(
    const int* __restrict__ src, const int* __restrict__ tgt,
    const float* __restrict__ ew, int* __restrict__ fill,
    int2* __restrict__ se, int E)
{
    const int e = blockIdx.x * blockDim.x + threadIdx.x;
    if (e >= E) return;
    const int pos = atomicAdd(fill + tgt[e], 1);
    se[pos] = make_int2(src[e], __float_as_int(ew[e]));
}

// ---------------------------------------------------------------------------
// Split-precision MFMA GEMM (R12-exact, 294.7us-verified): D = act(A@W+b).
// A*B ~= Ah*Bh + Ah*Bl + Al*Bh, f32 MFMA accum. 30 KB LDS -> 5 blocks/CU.
// ---------------------------------------------------------------------------
__global__ __launch_bounds__(256) void gemm_mfma(
    const float* __restrict__ A,
    const unsigned short* __restrict__ Bh0, const unsigned short* __restrict__ Bl0,
    const unsigned short* __restrict__ Bh1, const unsigned short* __restrict__ Bl1,
    const unsigned short* __restrict__ Bh2, const unsigned short* __restrict__ Bl2,
    const float* __restrict__ b0, const float* __restrict__ b1, const float* __restrict__ b2,
    float* __restrict__ D0, float* __restrict__ D1, float* __restrict__ D2,
    int V, int lrelu)
{
    __shared__ unsigned short Ash[64][40], Asl[64][40];     // 10 KB
    __shared__ unsigned short Bsh[128][40], Bsl[128][40];   // 20 KB

    const int m = blockIdx.y;
    const unsigned short* __restrict__ Wth = (m == 0) ? Bh0 : ((m == 1) ? Bh1 : Bh2);
    const unsigned short* __restrict__ Wtl = (m == 0) ? Bl0 : ((m == 1) ? Bl1 : Bl2);
    const float* __restrict__ bias         = (m == 0) ? b0  : ((m == 1) ? b1  : b2);
    float* __restrict__ D                  = (m == 0) ? D0  : ((m == 1) ? D1  : D2);

    const int tid  = threadIdx.x;
    const int w    = tid >> 6;
    const int l    = tid & 63;
    const int row0 = blockIdx.x * 64;

    const int srow = tid >> 2;      // A staging: row 0..63
    const int skc  = tid & 3;       // A staging: k-chunk 0..3

    f32x4 acc[8];
#pragma unroll
    for (int t = 0; t < 8; ++t) acc[t] = (f32x4){0.f, 0.f, 0.f, 0.f};

    for (int k0 = 0; k0 < 128; k0 += 32) {
        // stage A (64 rows x 32 k), f32 -> hi/lo bf16
        {
            const int gr = row0 + srow;
            float x[8] = {0.f, 0.f, 0.f, 0.f, 0.f, 0.f, 0.f, 0.f};
            if (gr < V) {
                const float4 a0 = *(const float4*)(A + (size_t)gr * 128 + k0 + skc * 8);
                const float4 a1 = *(const float4*)(A + (size_t)gr * 128 + k0 + skc * 8 + 4);
                x[0] = a0.x; x[1] = a0.y; x[2] = a0.z; x[3] = a0.w;
                x[4] = a1.x; x[5] = a1.y; x[6] = a1.z; x[7] = a1.w;
            }
            bf16x8 vh, vl;
#pragma unroll
            for (int i = 0; i < 8; ++i) {
                unsigned short hh, ll;
                splitf(x[i], hh, ll);
                vh[i] = (short)hh; vl[i] = (short)ll;
            }
            *(bf16x8*)&Ash[srow][skc * 8] = vh;
            *(bf16x8*)&Asl[srow][skc * 8] = vl;
        }
        // stage B (128 cols x 32 k) from pre-split transposed weights
#pragma unroll
        for (int r = 0; r < 2; ++r) {
            const int idx = tid + r * 256;
            const int n = idx >> 2, bkc = idx & 3;
            *(bf16x8*)&Bsh[n][bkc * 8] = *(const bf16x8*)(Wth + n * 128 + k0 + bkc * 8);
            *(bf16x8*)&Bsl[n][bkc * 8] = *(const bf16x8*)(Wtl + n * 128 + k0 + bkc * 8);
        }
        __syncthreads();

        const int ar  = w * 16 + (l & 15);
        const int kc8 = (l >> 4) * 8;
        const bf16x8 ah = *(const bf16x8*)&Ash[ar][kc8];
        const bf16x8 al = *(const bf16x8*)&Asl[ar][kc8];
#pragma unroll
        for (int t = 0; t < 8; ++t) {
            const int col = t * 16 + (l & 15);
            const bf16x8 bh = *(const bf16x8*)&Bsh[col][kc8];
            const bf16x8 bl = *(const bf16x8*)&Bsl[col][kc8];
            acc[t] = __builtin_amdgcn_mfma_f32_16x16x32_bf16(ah, bh, acc[t], 0, 0, 0);
            acc[t] = __builtin_amdgcn_mfma_f32_16x16x32_bf16(ah, bl, acc[t], 0, 0, 0);
            acc[t] = __builtin_amdgcn_mfma_f32_16x16x32_bf16(al, bh, acc[t], 0, 0, 0);
        }
        __syncthreads();
    }

    // epilogue: bias + optional lrelu; C/D frag col=lane&15, row=(lane>>4)*4+r
    const int colb = l & 15;
    const int rsub = (l >> 4) * 4;
#pragma unroll
    for (int t = 0; t < 8; ++t) {
        const int col = t * 16 + colb;
        const float bv = bias[col];
#pragma unroll
        for (int r = 0; r < 4; ++r) {
            const int grow = row0 + w * 16 + rsub + r;
            if (grow < V) {
                float xx = acc[t][r] + bv;
                if (lrelu) xx = (xx > 0.f) ? xx : NEG_SLOPE * xx;
                D[(size_t)grow * 128 + col] = xx;
            }
        }
    }
}

// ---------------------------------------------------------------------------
// Fused per-node kernel (all f32): QK^T + exp + denom + weighted Vv
// aggregation + normalization. One wave per node, STATIC mapping -- best of
// five scheduling variants (R4-R11); ~119 us, near the random-gather
// L2-miss floor (388 MB @ ~3.5 TB/s). Ksh padded [4][36]: conflict-free.
// ---------------------------------------------------------------------------
__global__ __launch_bounds__(256) void fused_agg(
    const float* __restrict__ Q, const float* __restrict__ K,
    const float* __restrict__ Vv, const int2* __restrict__ se,
    const int* __restrict__ offs, const int* __restrict__ fill,
    const float* __restrict__ Wei, const float* __restrict__ bei,
    float* __restrict__ accum, int V)
{
    __shared__ float Ksh[4][4][36];
    const int wid = threadIdx.x >> 6;
    const int node = blockIdx.x * 4 + wid;
    if (node >= V) return;
    const int l   = threadIdx.x & 63;
    const int h   = l & 3;
    const int hd  = l >> 4;
    const float weH = Wei[h], beH = bei[h];
    const float2* __restrict__ Vv2 = (const float2*)Vv;

    {
        const float2 kk = *(const float2*)(K + (size_t)node * 128 + l * 2);
        const int f0 = l * 2;
        Ksh[wid][f0 >> 5][f0 & 31] = kk.x;
        Ksh[wid][(f0 + 1) >> 5][(f0 + 1) & 31] = kk.y;
    }

    const int start = offs[node];
    const int end   = fill[node];

    float degacc = 0.f;
    float ax = 0.f, ay = 0.f;

    for (int b0 = start; b0 < end; b0 += 16) {
        const int nj = min(16, end - b0);
        const int jj = l >> 2;
        int   s = 0;
        float w = 0.f, p = 0.f;
        if (jj < nj) {
            const int2 t = se[b0 + jj];
            s = t.x;
            w = __int_as_float(t.y);
            const float4* qp = (const float4*)(Q + (size_t)s * 128 + h * 32);
            float dot = 0.f;
#pragma unroll
            for (int i = 0; i < 8; ++i) {
                const float4 q = qp[i];
                const float4 k = *(const float4*)&Ksh[wid][h][i * 4];
                dot += q.x * k.x + q.y * k.y + q.z * k.z + q.w * k.w;
            }
            float bb = fmaf(w, weH, beH);
            bb = (bb > 0.f) ? bb : NEG_SLOPE * bb;
            p = __expf(fmaf(dot, 0.17677669529663687f, bb));
        }
        degacc += p;
        const float coef = p * w;

        if (nj == 16) {
#pragma unroll
            for (int j = 0; j < 16; ++j) {
                const float cj = __shfl(coef, j * 4 + hd);
                const int   sj = __shfl(s,    j * 4);
                const float2 v = Vv2[(size_t)sj * 64 + l];
                ax = fmaf(cj, v.x, ax);
                ay = fmaf(cj, v.y, ay);
            }
        } else {
            for (int j = 0; j < nj; ++j) {
                const float cj = __shfl(coef, j * 4 + hd);
                const int   sj = __shfl(s,    j * 4);
                const float2 v = Vv2[(size_t)sj * 64 + l];
                ax = fmaf(cj, v.x, ax);
                ay = fmaf(cj, v.y, ay);
            }
        }
    }

    float d = degacc;
    d += __shfl_xor(d, 4);
    d += __shfl_xor(d, 8);
    d += __shfl_xor(d, 16);
    d += __shfl_xor(d, 32);
    const float deg = __shfl(d, hd);
    const float inv = 1.0f / (deg + 1e-16f);

    *(float2*)(accum + (size_t)node * 128 + l * 2) =
        make_float2(ax * inv, ay * inv);
}

// ---------------------------------------------------------------------------
extern "C" void kernel_launch(void* const* d_in, const int* in_sizes, int n_in,
                              void* d_out, int out_size, void* d_ws, size_t ws_size,
                              hipStream_t stream)
{
    const float* h   = (const float*)d_in[0];
    const int*   ei  = (const int*)  d_in[1];
    const float* ew  = (const float*)d_in[2];
    const float* Wq  = (const float*)d_in[3];
    const float* bq  = (const float*)d_in[4];
    const float* Wk  = (const float*)d_in[5];
    const float* bk  = (const float*)d_in[6];
    const float* Wv  = (const float*)d_in[7];
    const float* bv  = (const float*)d_in[8];
    const float* Wo  = (const float*)d_in[9];
    const float* bo  = (const float*)d_in[10];
    const float* Wei = (const float*)d_in[11];
    const float* bei = (const float*)d_in[12];

    const int V = in_sizes[0] / 128;
    const int E = in_sizes[2];
    const int* src = ei;
    const int* tgt = ei + E;

    // workspace layout
    float* Q     = (float*)d_ws;
    float* Km    = Q  + (size_t)V * 128;
    float* Vm    = Km + (size_t)V * 128;
    float* accum = Vm + (size_t)V * 128;
    unsigned short* Wth = (unsigned short*)(accum + (size_t)V * 128); // [4][128][128]
    unsigned short* Wtl = Wth + 4 * 16384;
    int2*  se    = (int2*)(Wtl + 4 * 16384);
    int*   cnt   = (int*)(se + E);
    int*   offs  = cnt  + V;
    int*   fill  = offs + V + 1;
    int*   bsums = fill + V;

    hipMemsetAsync(cnt, 0, (size_t)V * sizeof(int), stream);

    // prep: 4 weight splits (blocks 0..255) + in-degree count (rest)
    prep<<<256 + (E + 255) / 256, 256, 0, stream>>>(
        Wq, Wk, Wv, Wo, Wth, Wtl, tgt, cnt, E);

    const int mfGrid = (V + 63) / 64;
    gemm_mfma<<<dim3(mfGrid, 3), 256, 0, stream>>>(
        h, Wth, Wtl, Wth + 16384, Wtl + 16384, Wth + 2 * 16384, Wtl + 2 * 16384,
        bq, bk, bv, Q, Km, Vm, V, 0);

    const int nb = (V + 1023) / 1024;
    scan1<<<nb, 256, 0, stream>>>(cnt, offs, bsums, V);
    scan2<<<1, 64, 0, stream>>>(bsums, nb);
    scan3<<<(V + 255) / 256, 256, 0, stream>>>(offs, bsums, fill, V);
    scatter_edges<<<(E + 255) / 256, 256, 0, stream>>>(
        src, tgt, ew, fill, se, E);

    fused_agg<<<(V + 3) / 4, 256, 0, stream>>>(
        Q, Km, Vm, se, offs, fill, Wei, bei, accum, V);

    gemm_mfma<<<dim3(mfGrid, 1), 256, 0, stream>>>(
        accum, Wth + 3 * 16384, Wtl + 3 * 16384, Wth + 3 * 16384, Wtl + 3 * 16384,
        Wth + 3 * 16384, Wtl + 3 * 16384,
        bo, bo, bo, (float*)d_out, (float*)d_out, (float*)d_out, V, 1);
}

// Round 16
// 273.145 us; speedup vs baseline: 1.4440x; 1.0159x over previous
//
#include <hip/hip_runtime.h>
#include <hip/hip_bf16.h>

#define NEG_SLOPE 0.2f

typedef __attribute__((ext_vector_type(8))) short bf16x8;
typedef __attribute__((ext_vector_type(4))) float f32x4;

// split f32 -> bf16 hi + bf16 lo (RNE both); x ~= hi + lo with ~2^-17 residual
__device__ __forceinline__ void splitf(float x, unsigned short& h, unsigned short& l)
{
    const unsigned int u  = __float_as_uint(x);
    const unsigned int uh = (u + 0x7fffu + ((u >> 16) & 1u)) >> 16;
    const float        fh = __uint_as_float(uh << 16);
    const float        r  = x - fh;
    const unsigned int ur = __float_as_uint(r);
    const unsigned int ul = (ur + 0x7fffu + ((ur >> 16) & 1u)) >> 16;
    h = (unsigned short)uh;
    l = (unsigned short)ul;
}

// ---------------------------------------------------------------------------
// PREP: blocks 0..255 pre-split+transpose the 4 weight matrices; blocks 256+
// count in-degrees. (R15-verified: parallel merge saves ~17us vs 5 launches.)
// ---------------------------------------------------------------------------
__global__ __launch_bounds__(256) void prep(
    const float* __restrict__ Wq, const float* __restrict__ Wk,
    const float* __restrict__ Wv, const float* __restrict__ Wo,
    unsigned short* __restrict__ Wth, unsigned short* __restrict__ Wtl,
    const int* __restrict__ tgt, int* __restrict__ cnt, int E)
{
    const int bid = blockIdx.x;
    if (bid < 256) {
        const int mat = bid >> 6;
        const float* __restrict__ W =
            (mat == 0) ? Wq : ((mat == 1) ? Wk : ((mat == 2) ? Wv : Wo));
        const int t = (bid & 63) * 256 + threadIdx.x;   // 0..16383
        const int k = t >> 7, n = t & 127;
        unsigned short h, l;
        splitf(W[k * 128 + n], h, l);
        Wth[mat * 16384 + n * 128 + k] = h;
        Wtl[mat * 16384 + n * 128 + k] = l;
    } else {
        const int e = (bid - 256) * 256 + threadIdx.x;
        if (e < E) atomicAdd(cnt + tgt[e], 1);
    }
}

// ---------------------------------------------------------------------------
// CSR build: block-wise exclusive scan (49 blocks -- R14 lesson: keep scan
// traffic parallel across CUs, never single-block).
// ---------------------------------------------------------------------------
__global__ __launch_bounds__(256) void scan1(const int* __restrict__ cnt,
                                             int* __restrict__ offs,
                                             int* __restrict__ bsums, int V)
{
    __shared__ int sh[256];
    const int t = threadIdx.x;
    const int base = blockIdx.x * 1024;
    int v[4];
    int s = 0;
#pragma unroll
    for (int i = 0; i < 4; ++i) {
        const int idx = base + t * 4 + i;
        v[i] = (idx < V) ? cnt[idx] : 0;
        s += v[i];
    }
    sh[t] = s;
    __syncthreads();
    for (int off = 1; off < 256; off <<= 1) {
        const int x = (t >= off) ? sh[t - off] : 0;
        __syncthreads();
        sh[t] += x;
        __syncthreads();
    }
    int run = (t > 0) ? sh[t - 1] : 0;
#pragma unroll
    for (int i = 0; i < 4; ++i) {
        const int idx = base + t * 4 + i;
        if (idx < V) offs[idx] = run;
        run += v[i];
    }
    if (t == 255) bsums[blockIdx.x] = sh[255];
}

// scan3 with scan2 folded in: thread 0 computes the <=49-element bsums prefix
// for this block's 1024-chunk (each 256-wide block spans exactly one chunk).
__global__ __launch_bounds__(256) void scan3(int* __restrict__ offs,
                                             const int* __restrict__ bsums,
                                             int* __restrict__ fill, int V)
{
    __shared__ int pref;
    const int v = blockIdx.x * blockDim.x + threadIdx.x;
    const int chunk = (blockIdx.x * blockDim.x) >> 10;
    if (threadIdx.x == 0) {
        int s = 0;
        for (int i = 0; i < chunk; ++i) s += bsums[i];
        pref = s;
    }
    __syncthreads();
    if (v >= V) return;
    const int o = offs[v] + pref;
    offs[v] = o;
    fill[v] = o;
}

// ---------------------------------------------------------------------------
// Scatter edges into target-sorted order: packed (src, edge weight) int2.
// ---------------------------------------------------------------------------
__global__ __launch_bounds__(256) void scatter_edges(
    const int* __restrict__ src, const int* __restrict__ tgt,
    const float* __restrict__ ew, int* __restrict__ fill,
    int2* __restrict__ se, int E)
{
    const int e = blockIdx.x * blockDim.x + threadIdx.x;
    if (e >= E) return;
    const int pos = atomicAdd(fill + tgt[e], 1);
    se[pos] = make_int2(src[e], __float_as_int(ew[e]));
}

// ---------------------------------------------------------------------------
// Split-precision MFMA GEMM (R12-verified math): D = act(A@W+b), now with a
// per-output row stride ldD so Q and Vv can land interleaved in QV[V][256]
// (same-index gathers share a DRAM page in fused_agg -- R15 theory).
// ---------------------------------------------------------------------------
__global__ __launch_bounds__(256) void gemm_mfma(
    const float* __restrict__ A,
    const unsigned short* __restrict__ Bh0, const unsigned short* __restrict__ Bl0,
    const unsigned short* __restrict__ Bh1, const unsigned short* __restrict__ Bl1,
    const unsigned short* __restrict__ Bh2, const unsigned short* __restrict__ Bl2,
    const float* __restrict__ b0, const float* __restrict__ b1, const float* __restrict__ b2,
    float* __restrict__ D0, float* __restrict__ D1, float* __restrict__ D2,
    int ld0, int ld1, int ld2,
    int V, int lrelu)
{
    __shared__ unsigned short Ash[64][40], Asl[64][40];     // 10 KB
    __shared__ unsigned short Bsh[128][40], Bsl[128][40];   // 20 KB

    const int m = blockIdx.y;
    const unsigned short* __restrict__ Wth = (m == 0) ? Bh0 : ((m == 1) ? Bh1 : Bh2);
    const unsigned short* __restrict__ Wtl = (m == 0) ? Bl0 : ((m == 1) ? Bl1 : Bl2);
    const float* __restrict__ bias         = (m == 0) ? b0  : ((m == 1) ? b1  : b2);
    float* __restrict__ D                  = (m == 0) ? D0  : ((m == 1) ? D1  : D2);
    const int ldD                          = (m == 0) ? ld0 : ((m == 1) ? ld1 : ld2);

    const int tid  = threadIdx.x;
    const int w    = tid >> 6;
    const int l    = tid & 63;
    const int row0 = blockIdx.x * 64;

    const int srow = tid >> 2;      // A staging: row 0..63
    const int skc  = tid & 3;       // A staging: k-chunk 0..3

    f32x4 acc[8];
#pragma unroll
    for (int t = 0; t < 8; ++t) acc[t] = (f32x4){0.f, 0.f, 0.f, 0.f};

    for (int k0 = 0; k0 < 128; k0 += 32) {
        // stage A (64 rows x 32 k), f32 -> hi/lo bf16
        {
            const int gr = row0 + srow;
            float x[8] = {0.f, 0.f, 0.f, 0.f, 0.f, 0.f, 0.f, 0.f};
            if (gr < V) {
                const float4 a0 = *(const float4*)(A + (size_t)gr * 128 + k0 + skc * 8);
                const float4 a1 = *(const float4*)(A + (size_t)gr * 128 + k0 + skc * 8 + 4);
                x[0] = a0.x; x[1] = a0.y; x[2] = a0.z; x[3] = a0.w;
                x[4] = a1.x; x[5] = a1.y; x[6] = a1.z; x[7] = a1.w;
            }
            bf16x8 vh, vl;
#pragma unroll
            for (int i = 0; i < 8; ++i) {
                unsigned short hh, ll;
                splitf(x[i], hh, ll);
                vh[i] = (short)hh; vl[i] = (short)ll;
            }
            *(bf16x8*)&Ash[srow][skc * 8] = vh;
            *(bf16x8*)&Asl[srow][skc * 8] = vl;
        }
        // stage B (128 cols x 32 k) from pre-split transposed weights
#pragma unroll
        for (int r = 0; r < 2; ++r) {
            const int idx = tid + r * 256;
            const int n = idx >> 2, bkc = idx & 3;
            *(bf16x8*)&Bsh[n][bkc * 8] = *(const bf16x8*)(Wth + n * 128 + k0 + bkc * 8);
            *(bf16x8*)&Bsl[n][bkc * 8] = *(const bf16x8*)(Wtl + n * 128 + k0 + bkc * 8);
        }
        __syncthreads();

        const int ar  = w * 16 + (l & 15);
        const int kc8 = (l >> 4) * 8;
        const bf16x8 ah = *(const bf16x8*)&Ash[ar][kc8];
        const bf16x8 al = *(const bf16x8*)&Asl[ar][kc8];
#pragma unroll
        for (int t = 0; t < 8; ++t) {
            const int col = t * 16 + (l & 15);
            const bf16x8 bh = *(const bf16x8*)&Bsh[col][kc8];
            const bf16x8 bl = *(const bf16x8*)&Bsl[col][kc8];
            acc[t] = __builtin_amdgcn_mfma_f32_16x16x32_bf16(ah, bh, acc[t], 0, 0, 0);
            acc[t] = __builtin_amdgcn_mfma_f32_16x16x32_bf16(ah, bl, acc[t], 0, 0, 0);
            acc[t] = __builtin_amdgcn_mfma_f32_16x16x32_bf16(al, bh, acc[t], 0, 0, 0);
        }
        __syncthreads();
    }

    // epilogue: bias + optional lrelu; C/D frag col=lane&15, row=(lane>>4)*4+r
    const int colb = l & 15;
    const int rsub = (l >> 4) * 4;
#pragma unroll
    for (int t = 0; t < 8; ++t) {
        const int col = t * 16 + colb;
        const float bv = bias[col];
#pragma unroll
        for (int r = 0; r < 4; ++r) {
            const int grow = row0 + w * 16 + rsub + r;
            if (grow < V) {
                float xx = acc[t][r] + bv;
                if (lrelu) xx = (xx > 0.f) ? xx : NEG_SLOPE * xx;
                D[(size_t)grow * ldD + col] = xx;
            }
        }
    }
}

// ---------------------------------------------------------------------------
// Fused per-node kernel (all f32): QK^T + exp + denom + weighted Vv
// aggregation + normalization. One wave per node, STATIC mapping (best of
// six variants, R4-R11). Q and Vv interleaved in QV[V][256]: both gathers
// for edge-source s hit one contiguous 1 KB stretch (same DRAM page).
// Ksh padded [4][36]: conflict-free b128 broadcast reads.
// ---------------------------------------------------------------------------
__global__ __launch_bounds__(256) void fused_agg(
    const float* __restrict__ QV, const float* __restrict__ K,
    const int2* __restrict__ se,
    const int* __restrict__ offs, const int* __restrict__ fill,
    const float* __restrict__ Wei, const float* __restrict__ bei,
    float* __restrict__ accum, int V)
{
    __shared__ float Ksh[4][4][36];
    const int wid = threadIdx.x >> 6;
    const int node = blockIdx.x * 4 + wid;
    if (node >= V) return;
    const int l   = threadIdx.x & 63;
    const int h   = l & 3;
    const int hd  = l >> 4;
    const float weH = Wei[h], beH = bei[h];
    const float2* __restrict__ Vv2 = (const float2*)(QV + 128);  // row stride 256 f

    {
        const float2 kk = *(const float2*)(K + (size_t)node * 128 + l * 2);
        const int f0 = l * 2;
        Ksh[wid][f0 >> 5][f0 & 31] = kk.x;
        Ksh[wid][(f0 + 1) >> 5][(f0 + 1) & 31] = kk.y;
    }

    const int start = offs[node];
    const int end   = fill[node];

    float degacc = 0.f;
    float ax = 0.f, ay = 0.f;

    for (int b0 = start; b0 < end; b0 += 16) {
        const int nj = min(16, end - b0);
        const int jj = l >> 2;
        int   s = 0;
        float w = 0.f, p = 0.f;
        if (jj < nj) {
            const int2 t = se[b0 + jj];
            s = t.x;
            w = __int_as_float(t.y);
            const float4* qp = (const float4*)(QV + (size_t)s * 256 + h * 32);
            float dot = 0.f;
#pragma unroll
            for (int i = 0; i < 8; ++i) {
                const float4 q = qp[i];
                const float4 k = *(const float4*)&Ksh[wid][h][i * 4];
                dot += q.x * k.x + q.y * k.y + q.z * k.z + q.w * k.w;
            }
            float bb = fmaf(w, weH, beH);
            bb = (bb > 0.f) ? bb : NEG_SLOPE * bb;
            p = __expf(fmaf(dot, 0.17677669529663687f, bb));
        }
        degacc += p;
        const float coef = p * w;

        if (nj == 16) {
#pragma unroll
            for (int j = 0; j < 16; ++j) {
                const float cj = __shfl(coef, j * 4 + hd);
                const int   sj = __shfl(s,    j * 4);
                const float2 v = Vv2[(size_t)sj * 128 + l];
                ax = fmaf(cj, v.x, ax);
                ay = fmaf(cj, v.y, ay);
            }
        } else {
            for (int j = 0; j < nj; ++j) {
                const float cj = __shfl(coef, j * 4 + hd);
                const int   sj = __shfl(s,    j * 4);
                const float2 v = Vv2[(size_t)sj * 128 + l];
                ax = fmaf(cj, v.x, ax);
                ay = fmaf(cj, v.y, ay);
            }
        }
    }

    float d = degacc;
    d += __shfl_xor(d, 4);
    d += __shfl_xor(d, 8);
    d += __shfl_xor(d, 16);
    d += __shfl_xor(d, 32);
    const float deg = __shfl(d, hd);
    const float inv = 1.0f / (deg + 1e-16f);

    *(float2*)(accum + (size_t)node * 128 + l * 2) =
        make_float2(ax * inv, ay * inv);
}

// ---------------------------------------------------------------------------
extern "C" void kernel_launch(void* const* d_in, const int* in_sizes, int n_in,
                              void* d_out, int out_size, void* d_ws, size_t ws_size,
                              hipStream_t stream)
{
    const float* h   = (const float*)d_in[0];
    const int*   ei  = (const int*)  d_in[1];
    const float* ew  = (const float*)d_in[2];
    const float* Wq  = (const float*)d_in[3];
    const float* bq  = (const float*)d_in[4];
    const float* Wk  = (const float*)d_in[5];
    const float* bk  = (const float*)d_in[6];
    const float* Wv  = (const float*)d_in[7];
    const float* bv  = (const float*)d_in[8];
    const float* Wo  = (const float*)d_in[9];
    const float* bo  = (const float*)d_in[10];
    const float* Wei = (const float*)d_in[11];
    const float* bei = (const float*)d_in[12];

    const int V = in_sizes[0] / 128;
    const int E = in_sizes[2];
    const int* src = ei;
    const int* tgt = ei + E;

    // workspace layout
    float* QV    = (float*)d_ws;                     // [V][256]: Q | Vv interleaved
    float* Km    = QV + (size_t)V * 256;             // [V][128]
    float* accum = Km + (size_t)V * 128;             // [V][128]
    unsigned short* Wth = (unsigned short*)(accum + (size_t)V * 128); // [4][128][128]
    unsigned short* Wtl = Wth + 4 * 16384;
    int2*  se    = (int2*)(Wtl + 4 * 16384);
    int*   cnt   = (int*)(se + E);
    int*   offs  = cnt  + V;
    int*   fill  = offs + V + 1;
    int*   bsums = fill + V;

    hipMemsetAsync(cnt, 0, (size_t)V * sizeof(int), stream);

    // prep: 4 weight splits (blocks 0..255) + in-degree count (rest)
    prep<<<256 + (E + 255) / 256, 256, 0, stream>>>(
        Wq, Wk, Wv, Wo, Wth, Wtl, tgt, cnt, E);

    const int mfGrid = (V + 63) / 64;
    // Q -> QV[:, 0:128] (ld 256), K -> Km (ld 128), Vv -> QV[:, 128:256] (ld 256)
    gemm_mfma<<<dim3(mfGrid, 3), 256, 0, stream>>>(
        h, Wth, Wtl, Wth + 16384, Wtl + 16384, Wth + 2 * 16384, Wtl + 2 * 16384,
        bq, bk, bv, QV, Km, QV + 128, 256, 128, 256, V, 0);

    const int nb = (V + 1023) / 1024;
    scan1<<<nb, 256, 0, stream>>>(cnt, offs, bsums, V);
    scan3<<<(V + 255) / 256, 256, 0, stream>>>(offs, bsums, fill, V);
    scatter_edges<<<(E + 255) / 256, 256, 0, stream>>>(
        src, tgt, ew, fill, se, E);

    fused_agg<<<(V + 3) / 4, 256, 0, stream>>>(
        QV, Km, se, offs, fill, Wei, bei, accum, V);

    gemm_mfma<<<dim3(mfGrid, 1), 256, 0, stream>>>(
        accum, Wth + 3 * 16384, Wtl + 3 * 16384, Wth + 3 * 16384, Wtl + 3 * 16384,
        Wth + 3 * 16384, Wtl + 3 * 16384,
        bo, bo, bo, (float*)d_out, (float*)d_out, (float*)d_out,
        128, 128, 128, V, 1);
}

// Round 17
// 272.372 us; speedup vs baseline: 1.4481x; 1.0028x over previous
//
#include <hip/hip_runtime.h>
#include <hip/hip_bf16.h>

#define NEG_SLOPE 0.2f

typedef __attribute__((ext_vector_type(8))) short bf16x8;
typedef __attribute__((ext_vector_type(4))) float f32x4;

// split f32 -> bf16 hi + bf16 lo (RNE both); x ~= hi + lo with ~2^-17 residual
__device__ __forceinline__ void splitf(float x, unsigned short& h, unsigned short& l)
{
    const unsigned int u  = __float_as_uint(x);
    const unsigned int uh = (u + 0x7fffu + ((u >> 16) & 1u)) >> 16;
    const float        fh = __uint_as_float(uh << 16);
    const float        r  = x - fh;
    const unsigned int ur = __float_as_uint(r);
    const unsigned int ul = (ur + 0x7fffu + ((ur >> 16) & 1u)) >> 16;
    h = (unsigned short)uh;
    l = (unsigned short)ul;
}

// ---------------------------------------------------------------------------
// PREP: blocks 0..15 pre-split+transpose the 4 weight matrices via LDS-tiled
// 64x64 transpose (R16 fix: old version wrote 2-byte stores at stride-128 --
// fully uncoalesced; now both load and store are contiguous per wave).
// Blocks 16+ count in-degrees. [64][66] padding -> conflict-free LDS.
// ---------------------------------------------------------------------------
__global__ __launch_bounds__(256) void prep(
    const float* __restrict__ Wq, const float* __restrict__ Wk,
    const float* __restrict__ Wv, const float* __restrict__ Wo,
    unsigned short* __restrict__ Wth, unsigned short* __restrict__ Wtl,
    const int* __restrict__ tgt, int* __restrict__ cnt, int E)
{
    const int bid = blockIdx.x;
    if (bid < 16) {
        __shared__ unsigned short shh[64][66], shl[64][66];
        const int mat = bid >> 2;
        const float* __restrict__ W =
            (mat == 0) ? Wq : ((mat == 1) ? Wk : ((mat == 2) ? Wv : Wo));
        const int k0 = ((bid >> 1) & 1) * 64;
        const int n0 = (bid & 1) * 64;
        const int tid = threadIdx.x;
        // phase 1: coalesced load W[k0+i][n0+j], split into LDS
#pragma unroll
        for (int p = 0; p < 16; ++p) {
            const int i = p * 4 + (tid >> 6);
            const int j = tid & 63;
            unsigned short h, l;
            splitf(W[(size_t)(k0 + i) * 128 + n0 + j], h, l);
            shh[i][j] = h;
            shl[i][j] = l;
        }
        __syncthreads();
        // phase 2: coalesced store Wt[n0+jn][k0+ik] (ik consecutive per wave)
#pragma unroll
        for (int p = 0; p < 16; ++p) {
            const int jn = p * 4 + (tid >> 6);
            const int ik = tid & 63;
            const size_t o = (size_t)mat * 16384 + (size_t)(n0 + jn) * 128 + k0 + ik;
            Wth[o] = shh[ik][jn];
            Wtl[o] = shl[ik][jn];
        }
    } else {
        const int e = (bid - 16) * 256 + threadIdx.x;
        if (e < E) atomicAdd(cnt + tgt[e], 1);
    }
}

// ---------------------------------------------------------------------------
// CSR build: block-wise exclusive scan (49 blocks -- R14 lesson: keep scan
// traffic parallel across CUs, never single-block).
// ---------------------------------------------------------------------------
__global__ __launch_bounds__(256) void scan1(const int* __restrict__ cnt,
                                             int* __restrict__ offs,
                                             int* __restrict__ bsums, int V)
{
    __shared__ int sh[256];
    const int t = threadIdx.x;
    const int base = blockIdx.x * 1024;
    int v[4];
    int s = 0;
#pragma unroll
    for (int i = 0; i < 4; ++i) {
        const int idx = base + t * 4 + i;
        v[i] = (idx < V) ? cnt[idx] : 0;
        s += v[i];
    }
    sh[t] = s;
    __syncthreads();
    for (int off = 1; off < 256; off <<= 1) {
        const int x = (t >= off) ? sh[t - off] : 0;
        __syncthreads();
        sh[t] += x;
        __syncthreads();
    }
    int run = (t > 0) ? sh[t - 1] : 0;
#pragma unroll
    for (int i = 0; i < 4; ++i) {
        const int idx = base + t * 4 + i;
        if (idx < V) offs[idx] = run;
        run += v[i];
    }
    if (t == 255) bsums[blockIdx.x] = sh[255];
}

// scan3 with scan2 folded in. R16 fix: the <=49-element bsums prefix is now
// loaded by 64 parallel lanes + shfl reduce (was a serial thread-0 loop =
// ~49 L2 latencies for late blocks).
__global__ __launch_bounds__(256) void scan3(int* __restrict__ offs,
                                             const int* __restrict__ bsums,
                                             int* __restrict__ fill, int V)
{
    __shared__ int pref;
    const int v = blockIdx.x * blockDim.x + threadIdx.x;
    const int chunk = (blockIdx.x * blockDim.x) >> 10;
    if (threadIdx.x < 64) {
        int x = (threadIdx.x < chunk) ? bsums[threadIdx.x] : 0;
        x += __shfl_xor(x, 1);
        x += __shfl_xor(x, 2);
        x += __shfl_xor(x, 4);
        x += __shfl_xor(x, 8);
        x += __shfl_xor(x, 16);
        x += __shfl_xor(x, 32);
        if (threadIdx.x == 0) pref = x;
    }
    __syncthreads();
    if (v >= V) return;
    const int o = offs[v] + pref;
    offs[v] = o;
    fill[v] = o;
}

// ---------------------------------------------------------------------------
// Scatter edges into target-sorted order: packed (src, edge weight) int2.
// ---------------------------------------------------------------------------
__global__ __launch_bounds__(256) void scatter_edges(
    const int* __restrict__ src, const int* __restrict__ tgt,
    const float* __restrict__ ew, int* __restrict__ fill,
    int2* __restrict__ se, int E)
{
    const int e = blockIdx.x * blockDim.x + threadIdx.x;
    if (e >= E) return;
    const int pos = atomicAdd(fill + tgt[e], 1);
    se[pos] = make_int2(src[e], __float_as_int(ew[e]));
}

// ---------------------------------------------------------------------------
// Split-precision MFMA GEMM (R12-verified math, R16-exact): D = act(A@W+b),
// per-output row stride ldD (Q/Vv interleaved in QV[V][256]).
// ---------------------------------------------------------------------------
__global__ __launch_bounds__(256) void gemm_mfma(
    const float* __restrict__ A,
    const unsigned short* __restrict__ Bh0, const unsigned short* __restrict__ Bl0,
    const unsigned short* __restrict__ Bh1, const unsigned short* __restrict__ Bl1,
    const unsigned short* __restrict__ Bh2, const unsigned short* __restrict__ Bl2,
    const float* __restrict__ b0, const float* __restrict__ b1, const float* __restrict__ b2,
    float* __restrict__ D0, float* __restrict__ D1, float* __restrict__ D2,
    int ld0, int ld1, int ld2,
    int V, int lrelu)
{
    __shared__ unsigned short Ash[64][40], Asl[64][40];     // 10 KB
    __shared__ unsigned short Bsh[128][40], Bsl[128][40];   // 20 KB

    const int m = blockIdx.y;
    const unsigned short* __restrict__ Wth = (m == 0) ? Bh0 : ((m == 1) ? Bh1 : Bh2);
    const unsigned short* __restrict__ Wtl = (m == 0) ? Bl0 : ((m == 1) ? Bl1 : Bl2);
    const float* __restrict__ bias         = (m == 0) ? b0  : ((m == 1) ? b1  : b2);
    float* __restrict__ D                  = (m == 0) ? D0  : ((m == 1) ? D1  : D2);
    const int ldD                          = (m == 0) ? ld0 : ((m == 1) ? ld1 : ld2);

    const int tid  = threadIdx.x;
    const int w    = tid >> 6;
    const int l    = tid & 63;
    const int row0 = blockIdx.x * 64;

    const int srow = tid >> 2;      // A staging: row 0..63
    const int skc  = tid & 3;       // A staging: k-chunk 0..3

    f32x4 acc[8];
#pragma unroll
    for (int t = 0; t < 8; ++t) acc[t] = (f32x4){0.f, 0.f, 0.f, 0.f};

    for (int k0 = 0; k0 < 128; k0 += 32) {
        // stage A (64 rows x 32 k), f32 -> hi/lo bf16
        {
            const int gr = row0 + srow;
            float x[8] = {0.f, 0.f, 0.f, 0.f, 0.f, 0.f, 0.f, 0.f};
            if (gr < V) {
                const float4 a0 = *(const float4*)(A + (size_t)gr * 128 + k0 + skc * 8);
                const float4 a1 = *(const float4*)(A + (size_t)gr * 128 + k0 + skc * 8 + 4);
                x[0] = a0.x; x[1] = a0.y; x[2] = a0.z; x[3] = a0.w;
                x[4] = a1.x; x[5] = a1.y; x[6] = a1.z; x[7] = a1.w;
            }
            bf16x8 vh, vl;
#pragma unroll
            for (int i = 0; i < 8; ++i) {
                unsigned short hh, ll;
                splitf(x[i], hh, ll);
                vh[i] = (short)hh; vl[i] = (short)ll;
            }
            *(bf16x8*)&Ash[srow][skc * 8] = vh;
            *(bf16x8*)&Asl[srow][skc * 8] = vl;
        }
        // stage B (128 cols x 32 k) from pre-split transposed weights
#pragma unroll
        for (int r = 0; r < 2; ++r) {
            const int idx = tid + r * 256;
            const int n = idx >> 2, bkc = idx & 3;
            *(bf16x8*)&Bsh[n][bkc * 8] = *(const bf16x8*)(Wth + n * 128 + k0 + bkc * 8);
            *(bf16x8*)&Bsl[n][bkc * 8] = *(const bf16x8*)(Wtl + n * 128 + k0 + bkc * 8);
        }
        __syncthreads();

        const int ar  = w * 16 + (l & 15);
        const int kc8 = (l >> 4) * 8;
        const bf16x8 ah = *(const bf16x8*)&Ash[ar][kc8];
        const bf16x8 al = *(const bf16x8*)&Asl[ar][kc8];
#pragma unroll
        for (int t = 0; t < 8; ++t) {
            const int col = t * 16 + (l & 15);
            const bf16x8 bh = *(const bf16x8*)&Bsh[col][kc8];
            const bf16x8 bl = *(const bf16x8*)&Bsl[col][kc8];
            acc[t] = __builtin_amdgcn_mfma_f32_16x16x32_bf16(ah, bh, acc[t], 0, 0, 0);
            acc[t] = __builtin_amdgcn_mfma_f32_16x16x32_bf16(ah, bl, acc[t], 0, 0, 0);
            acc[t] = __builtin_amdgcn_mfma_f32_16x16x32_bf16(al, bh, acc[t], 0, 0, 0);
        }
        __syncthreads();
    }

    // epilogue: bias + optional lrelu; C/D frag col=lane&15, row=(lane>>4)*4+r
    const int colb = l & 15;
    const int rsub = (l >> 4) * 4;
#pragma unroll
    for (int t = 0; t < 8; ++t) {
        const int col = t * 16 + colb;
        const float bv = bias[col];
#pragma unroll
        for (int r = 0; r < 4; ++r) {
            const int grow = row0 + w * 16 + rsub + r;
            if (grow < V) {
                float xx = acc[t][r] + bv;
                if (lrelu) xx = (xx > 0.f) ? xx : NEG_SLOPE * xx;
                D[(size_t)grow * ldD + col] = xx;
            }
        }
    }
}

// ---------------------------------------------------------------------------
// Fused per-node kernel (R16-exact): QK^T + exp + denom + weighted Vv
// aggregation + normalization. One wave per node, STATIC mapping. Pinned at
// ~119us across 7 structural variants (R4-R16) -- treated as the gather
// floor for this decomposition. Ksh padded [4][36]: conflict-free.
// ---------------------------------------------------------------------------
__global__ __launch_bounds__(256) void fused_agg(
    const float* __restrict__ QV, const float* __restrict__ K,
    const int2* __restrict__ se,
    const int* __restrict__ offs, const int* __restrict__ fill,
    const float* __restrict__ Wei, const float* __restrict__ bei,
    float* __restrict__ accum, int V)
{
    __shared__ float Ksh[4][4][36];
    const int wid = threadIdx.x >> 6;
    const int node = blockIdx.x * 4 + wid;
    if (node >= V) return;
    const int l   = threadIdx.x & 63;
    const int h   = l & 3;
    const int hd  = l >> 4;
    const float weH = Wei[h], beH = bei[h];
    const float2* __restrict__ Vv2 = (const float2*)(QV + 128);  // row stride 256 f

    {
        const float2 kk = *(const float2*)(K + (size_t)node * 128 + l * 2);
        const int f0 = l * 2;
        Ksh[wid][f0 >> 5][f0 & 31] = kk.x;
        Ksh[wid][(f0 + 1) >> 5][(f0 + 1) & 31] = kk.y;
    }

    const int start = offs[node];
    const int end   = fill[node];

    float degacc = 0.f;
    float ax = 0.f, ay = 0.f;

    for (int b0 = start; b0 < end; b0 += 16) {
        const int nj = min(16, end - b0);
        const int jj = l >> 2;
        int   s = 0;
        float w = 0.f, p = 0.f;
        if (jj < nj) {
            const int2 t = se[b0 + jj];
            s = t.x;
            w = __int_as_float(t.y);
            const float4* qp = (const float4*)(QV + (size_t)s * 256 + h * 32);
            float dot = 0.f;
#pragma unroll
            for (int i = 0; i < 8; ++i) {
                const float4 q = qp[i];
                const float4 k = *(const float4*)&Ksh[wid][h][i * 4];
                dot += q.x * k.x + q.y * k.y + q.z * k.z + q.w * k.w;
            }
            float bb = fmaf(w, weH, beH);
            bb = (bb > 0.f) ? bb : NEG_SLOPE * bb;
            p = __expf(fmaf(dot, 0.17677669529663687f, bb));
        }
        degacc += p;
        const float coef = p * w;

        if (nj == 16) {
#pragma unroll
            for (int j = 0; j < 16; ++j) {
                const float cj = __shfl(coef, j * 4 + hd);
                const int   sj = __shfl(s,    j * 4);
                const float2 v = Vv2[(size_t)sj * 128 + l];
                ax = fmaf(cj, v.x, ax);
                ay = fmaf(cj, v.y, ay);
            }
        } else {
            for (int j = 0; j < nj; ++j) {
                const float cj = __shfl(coef, j * 4 + hd);
                const int   sj = __shfl(s,    j * 4);
                const float2 v = Vv2[(size_t)sj * 128 + l];
                ax = fmaf(cj, v.x, ax);
                ay = fmaf(cj, v.y, ay);
            }
        }
    }

    float d = degacc;
    d += __shfl_xor(d, 4);
    d += __shfl_xor(d, 8);
    d += __shfl_xor(d, 16);
    d += __shfl_xor(d, 32);
    const float deg = __shfl(d, hd);
    const float inv = 1.0f / (deg + 1e-16f);

    *(float2*)(accum + (size_t)node * 128 + l * 2) =
        make_float2(ax * inv, ay * inv);
}

// ---------------------------------------------------------------------------
extern "C" void kernel_launch(void* const* d_in, const int* in_sizes, int n_in,
                              void* d_out, int out_size, void* d_ws, size_t ws_size,
                              hipStream_t stream)
{
    const float* h   = (const float*)d_in[0];
    const int*   ei  = (const int*)  d_in[1];
    const float* ew  = (const float*)d_in[2];
    const float* Wq  = (const float*)d_in[3];
    const float* bq  = (const float*)d_in[4];
    const float* Wk  = (const float*)d_in[5];
    const float* bk  = (const float*)d_in[6];
    const float* Wv  = (const float*)d_in[7];
    const float* bv  = (const float*)d_in[8];
    const float* Wo  = (const float*)d_in[9];
    const float* bo  = (const float*)d_in[10];
    const float* Wei = (const float*)d_in[11];
    const float* bei = (const float*)d_in[12];

    const int V = in_sizes[0] / 128;
    const int E = in_sizes[2];
    const int* src = ei;
    const int* tgt = ei + E;

    // workspace layout
    float* QV    = (float*)d_ws;                     // [V][256]: Q | Vv interleaved
    float* Km    = QV + (size_t)V * 256;             // [V][128]
    float* accum = Km + (size_t)V * 128;             // [V][128]
    unsigned short* Wth = (unsigned short*)(accum + (size_t)V * 128); // [4][128][128]
    unsigned short* Wtl = Wth + 4 * 16384;
    int2*  se    = (int2*)(Wtl + 4 * 16384);
    int*   cnt   = (int*)(se + E);
    int*   offs  = cnt  + V;
    int*   fill  = offs + V + 1;
    int*   bsums = fill + V;

    hipMemsetAsync(cnt, 0, (size_t)V * sizeof(int), stream);

    // prep: 4 weight splits via LDS transpose (blocks 0..15) + in-degree count
    prep<<<16 + (E + 255) / 256, 256, 0, stream>>>(
        Wq, Wk, Wv, Wo, Wth, Wtl, tgt, cnt, E);

    const int mfGrid = (V + 63) / 64;
    // Q -> QV[:, 0:128] (ld 256), K -> Km (ld 128), Vv -> QV[:, 128:256] (ld 256)
    gemm_mfma<<<dim3(mfGrid, 3), 256, 0, stream>>>(
        h, Wth, Wtl, Wth + 16384, Wtl + 16384, Wth + 2 * 16384, Wtl + 2 * 16384,
        bq, bk, bv, QV, Km, QV + 128, 256, 128, 256, V, 0);

    const int nb = (V + 1023) / 1024;
    scan1<<<nb, 256, 0, stream>>>(cnt, offs, bsums, V);
    scan3<<<(V + 255) / 256, 256, 0, stream>>>(offs, bsums, fill, V);
    scatter_edges<<<(E + 255) / 256, 256, 0, stream>>>(
        src, tgt, ew, fill, se, E);

    fused_agg<<<(V + 3) / 4, 256, 0, stream>>>(
        QV, Km, se, offs, fill, Wei, bei, accum, V);

    gemm_mfma<<<dim3(mfGrid, 1), 256, 0, stream>>>(
        accum, Wth + 3 * 16384, Wtl + 3 * 16384, Wth + 3 * 16384, Wtl + 3 * 16384,
        Wth + 3 * 16384, Wtl + 3 * 16384,
        bo, bo, bo, (float*)d_out, (float*)d_out, (float*)d_out,
        128, 128, 128, V, 1);
}